// Round 3
// baseline (335.869 us; speedup 1.0000x reference)
//
#include <hip/hip_runtime.h>

// GRU cell, fused single pass. B = 4,194,304 rows, DX = 10, DH = 4, fp32.
// DRAM floor ~185 MB (L3 absorbs part of x) -> ~29 us at 6.3 TB/s.
//
// R2 design (R1 ran 110 us: wave-uniform j made all 4 waves load the SAME
// rows -> ~4x L1 line-lookups, plus a barrier per iteration; VALUBusy only
// 30%, HBM 21% -> L1-request/latency bound):
//  - back to quad decomposition j = tid&3 (R0): 4 lanes of a quad share a row,
//    so their identical x/h loads coalesce to one address within each
//    instruction (no duplicate L1 traffic), stores are dense dwords, and
//    there is NO LDS / NO barrier -> iterations overlap freely.
//  - fix R0's real bug (VGPR_Count=36, weights re-fetched every iter):
//    weights are PINNED in VGPRs via asm("" : "+v") -- asm-defined values
//    cannot be rematerialized, so they stay live across the loop.
//    __launch_bounds__(256,4) allows up to 128 VGPRs.
//  - fast transcendentals (v_exp_f32 + v_rcp_f32), with log2(e) factors
//    pre-folded into the weights: sigmoid = rcp(1+exp2(dot_negscaled)),
//    tanh(t) = 1 - 2*rcp(1+exp2(2*log2e*t)).

constexpr int DXc = 10;
constexpr int DHc = 4;

__device__ __forceinline__ float pin(float v) {
    asm volatile("" : "+v"(v));   // force into a VGPR; defeat rematerialization
    return v;
}

__global__ __launch_bounds__(256, 4)
void gru_fused(const float* __restrict__ x,
               const float* __restrict__ hidden,
               const float* __restrict__ Wzh, const float* __restrict__ bzh,
               const float* __restrict__ Wzx, const float* __restrict__ bzx,
               const float* __restrict__ Wrh, const float* __restrict__ brh,
               const float* __restrict__ Wrx, const float* __restrict__ brx,
               const float* __restrict__ Wnx, const float* __restrict__ bnx,
               const float* __restrict__ Wnh, const float* __restrict__ bnh,
               float* __restrict__ out, int total /* = B*DH */)
{
    const int tid = blockIdx.x * blockDim.x + threadIdx.x;
    const int nth = gridDim.x * blockDim.x;   // multiple of 4 -> j invariant
    const int j   = tid & 3;                  // output unit of this thread

    const float kL2E = 1.44269504088896f;     // log2(e)
    const float sZ = -kL2E;                   // sigmoid: rcp(1+exp2(-log2e*a))
    const float sR = -kL2E;
    const float sN = 2.0f * kL2E;             // tanh: 1-2*rcp(1+exp2(2log2e*t))

    // ---- j-th weight rows -> pinned VGPRs, pre-scaled (once) ----
    float wzh[DHc], wrh[DHc], wnh[DHc];
    float wzx[DXc], wrx[DXc], wnx[DXc];
    {
        const float4 a = *reinterpret_cast<const float4*>(Wzh + j * DHc);
        const float4 b = *reinterpret_cast<const float4*>(Wrh + j * DHc);
        const float4 c = *reinterpret_cast<const float4*>(Wnh + j * DHc);
        const float az4[4] = {a.x, a.y, a.z, a.w};
        const float br4[4] = {b.x, b.y, b.z, b.w};
        const float cn4[4] = {c.x, c.y, c.z, c.w};
#pragma unroll
        for (int k = 0; k < DHc; ++k) {
            wzh[k] = pin(az4[k] * sZ);
            wrh[k] = pin(br4[k] * sR);
            wnh[k] = pin(cn4[k] * sN);
        }
        const float2* pz = reinterpret_cast<const float2*>(Wzx + j * DXc);
        const float2* pr = reinterpret_cast<const float2*>(Wrx + j * DXc);
        const float2* pn = reinterpret_cast<const float2*>(Wnx + j * DXc);
#pragma unroll
        for (int q = 0; q < DXc / 2; ++q) {
            const float2 z2 = pz[q], r2 = pr[q], n2 = pn[q];
            wzx[2 * q]     = pin(z2.x * sZ);
            wzx[2 * q + 1] = pin(z2.y * sZ);
            wrx[2 * q]     = pin(r2.x * sR);
            wrx[2 * q + 1] = pin(r2.y * sR);
            wnx[2 * q]     = pin(n2.x * sN);
            wnx[2 * q + 1] = pin(n2.y * sN);
        }
    }
    const float bz    = pin((bzh[j] + bzx[j]) * sZ);
    const float br    = pin((brh[j] + brx[j]) * sR);
    const float bnh_j = pin(bnh[j] * sN);
    const float bnx_j = pin(bnx[j] * sN);

    for (int p = tid; p < total; p += nth) {
        const int row = p >> 2;

        // x row: 5 x float2 (8 B aligned); quad lanes share addresses ->
        // same-address coalescing inside each instruction.
        const float2* xr = reinterpret_cast<const float2*>(x + row * DXc);
        const float2 x0 = xr[0], x1 = xr[1], x2 = xr[2], x3 = xr[3], x4 = xr[4];
        const float4 hv = *reinterpret_cast<const float4*>(hidden + row * DHc);
        const float xv[DXc]  = {x0.x, x0.y, x1.x, x1.y, x2.x,
                                x2.y, x3.x, x3.y, x4.x, x4.y};
        const float hvv[DHc] = {hv.x, hv.y, hv.z, hv.w};

        float az = bz, ar = br, ah = bnh_j, ax = bnx_j;
#pragma unroll
        for (int k = 0; k < DHc; ++k) {
            az = fmaf(hvv[k], wzh[k], az);
            ar = fmaf(hvv[k], wrh[k], ar);
            ah = fmaf(hvv[k], wnh[k], ah);
        }
#pragma unroll
        for (int k = 0; k < DXc; ++k) {
            az = fmaf(xv[k], wzx[k], az);
            ar = fmaf(xv[k], wrx[k], ar);
            ax = fmaf(xv[k], wnx[k], ax);
        }

        // z = sigmoid, r = sigmoid, n = tanh -- scales pre-folded above.
        const float z = __builtin_amdgcn_rcpf(1.0f + __builtin_amdgcn_exp2f(az));
        const float r = __builtin_amdgcn_rcpf(1.0f + __builtin_amdgcn_exp2f(ar));
        const float t = fmaf(r, ah, ax);
        const float n = fmaf(-2.0f,
                             __builtin_amdgcn_rcpf(1.0f + __builtin_amdgcn_exp2f(t)),
                             1.0f);

        const float hj = (j == 0) ? hv.x : (j == 1) ? hv.y : (j == 2) ? hv.z : hv.w;
        out[p] = fmaf(z, hj - n, n);     // (1-z)*n + z*h
    }
}

extern "C" void kernel_launch(void* const* d_in, const int* in_sizes, int n_in,
                              void* d_out, int out_size, void* d_ws, size_t ws_size,
                              hipStream_t stream) {
    const float* x   = (const float*)d_in[0];
    const float* h   = (const float*)d_in[1];
    const float* Wzh = (const float*)d_in[2];
    const float* bzh = (const float*)d_in[3];
    const float* Wzx = (const float*)d_in[4];
    const float* bzx = (const float*)d_in[5];
    const float* Wrh = (const float*)d_in[6];
    const float* brh = (const float*)d_in[7];
    const float* Wrx = (const float*)d_in[8];
    const float* brx = (const float*)d_in[9];
    const float* Wnx = (const float*)d_in[10];
    const float* bnx = (const float*)d_in[11];
    const float* Wnh = (const float*)d_in[12];
    const float* bnh = (const float*)d_in[13];
    float* out = (float*)d_out;

    const int total = out_size;   // B * DH = 16,777,216
    const int block = 256;
    const int grid  = 2048;       // grid-stride, 32 iters, preamble amortized

    gru_fused<<<grid, block, 0, stream>>>(x, h, Wzh, bzh, Wzx, bzx,
                                          Wrh, brh, Wrx, brx,
                                          Wnx, bnx, Wnh, bnh, out, total);
}

// Round 5
// 311.361 us; speedup vs baseline: 1.0787x; 1.0787x over previous
//
#include <hip/hip_runtime.h>

// GRU cell, fused single pass. B = 4,194,304 rows, DX = 10, DH = 4, fp32.
// DRAM traffic ~185 MB -> ~29 us floor at 6.3 TB/s.
//
// R4 = R3 resubmitted verbatim (R3's bench died on container infra, not the
// kernel). Design rationale:
// R0/R1/R2 all pinned at ~110-119 us with HBM ~19% and VALU <=50%:
// latency-bound on strided per-row global loads (5x stride-40B float2 for x)
// plus per-iteration weight refetch (VGPR pin failed twice: VGPR_Count=36).
//  - x: block-staged through LDS. 512-row tile = 1280 float4, loaded as 5
//    dense lane-contiguous float4 per thread (the measured-6.3TB/s pattern),
//    ds_write_b128 linear. Compute reads x rows from LDS.
//  - weights: SGPR-resident (proven in R1, SGPR_Count=80) -> j must be
//    wave-uniform: wave w computes unit w for all 512 rows (8 iters of 64).
//    FMA takes the SGPR operand directly; zero VGPR cost.
//  - h: per-lane dense float4 loads in compute loop (rows = lane-contiguous).
//  - out: 8 results/thread kept in regs; end-of-tile LDS transpose with
//    pad-5 layout (<=2-way banks on both write and read), then dense dword
//    stores. Transpose buffer reuses the x LDS region.
//  - fast transcendentals, log2e pre-folded into SGPR weights.
//  - B = 512 * 8192 exactly: no tails, one tile per block.

constexpr int DXc = 10;
constexpr int DHc = 4;
constexpr int TR  = 512;                 // tile rows per block
constexpr int XF4 = TR * DXc / 4;        // 1280 float4 per x tile

__device__ __forceinline__ float sgpr_f(float v) {
    // Force a wave-uniform value into an SGPR.
    return __uint_as_float(__builtin_amdgcn_readfirstlane(__float_as_uint(v)));
}

__global__ __launch_bounds__(256, 4)
void gru_fused(const float* __restrict__ x,
               const float* __restrict__ hidden,
               const float* __restrict__ Wzh, const float* __restrict__ bzh,
               const float* __restrict__ Wzx, const float* __restrict__ bzx,
               const float* __restrict__ Wrh, const float* __restrict__ brh,
               const float* __restrict__ Wrx, const float* __restrict__ brx,
               const float* __restrict__ Wnx, const float* __restrict__ bnx,
               const float* __restrict__ Wnh, const float* __restrict__ bnh,
               float* __restrict__ out)
{
    __shared__ float xs[TR * DXc];       // 20480 B; reused as transpose buffer

    const int t    = threadIdx.x;
    const int lane = t & 63;
    const int j    = __builtin_amdgcn_readfirstlane(t >> 6);   // unit 0..3
    const int tile = blockIdx.x * TR;

    // ---- stage x tile: dense float4 global -> LDS ----
    {
        const float4* xg = reinterpret_cast<const float4*>(x) + blockIdx.x * XF4;
        float4* xl = reinterpret_cast<float4*>(xs);
#pragma unroll
        for (int q = 0; q < 5; ++q)
            xl[q * 256 + t] = xg[q * 256 + t];
    }

    // ---- weights -> SGPRs, pre-scaled by +/-log2(e) (once) ----
    const float kL2E = 1.44269504088896f;
    const float sZ = -kL2E;              // sigmoid(a) = rcp(1 + exp2(-log2e*a))
    const float sN = 2.0f * kL2E;        // tanh(t) = 1 - 2*rcp(1 + exp2(2log2e*t))

    float wzh[DHc], wrh[DHc], wnh[DHc];
    float wzx[DXc], wrx[DXc], wnx[DXc];
#pragma unroll
    for (int k = 0; k < DHc; ++k) {
        wzh[k] = sgpr_f(Wzh[j * DHc + k] * sZ);
        wrh[k] = sgpr_f(Wrh[j * DHc + k] * sZ);
        wnh[k] = sgpr_f(Wnh[j * DHc + k] * sN);
    }
#pragma unroll
    for (int k = 0; k < DXc; ++k) {
        wzx[k] = sgpr_f(Wzx[j * DXc + k] * sZ);
        wrx[k] = sgpr_f(Wrx[j * DXc + k] * sZ);
        wnx[k] = sgpr_f(Wnx[j * DXc + k] * sN);
    }
    const float bz    = sgpr_f((bzh[j] + bzx[j]) * sZ);
    const float br    = sgpr_f((brh[j] + brx[j]) * sZ);
    const float bnh_j = sgpr_f(bnh[j] * sN);
    const float bnx_j = sgpr_f(bnx[j] * sN);

    __syncthreads();

    // ---- compute: wave j does unit j for rows lane + 64k, k = 0..7 ----
    float o[8];
#pragma unroll
    for (int k = 0; k < 8; ++k) {
        const int rl = lane + (k << 6);

        const float2* xr = reinterpret_cast<const float2*>(xs + rl * DXc);
        const float2 a0 = xr[0], a1 = xr[1], a2 = xr[2], a3 = xr[3], a4 = xr[4];
        const float xv[DXc] = {a0.x, a0.y, a1.x, a1.y, a2.x,
                               a2.y, a3.x, a3.y, a4.x, a4.y};

        const float4 hv = *reinterpret_cast<const float4*>(hidden + (tile + rl) * DHc);
        const float hvv[DHc] = {hv.x, hv.y, hv.z, hv.w};

        float az = bz, ar = br, ah = bnh_j, ax = bnx_j;
#pragma unroll
        for (int c = 0; c < DHc; ++c) {
            az = fmaf(hvv[c], wzh[c], az);
            ar = fmaf(hvv[c], wrh[c], ar);
            ah = fmaf(hvv[c], wnh[c], ah);
        }
#pragma unroll
        for (int c = 0; c < DXc; ++c) {
            az = fmaf(xv[c], wzx[c], az);
            ar = fmaf(xv[c], wrx[c], ar);
            ax = fmaf(xv[c], wnx[c], ax);
        }

        const float z  = __builtin_amdgcn_rcpf(1.0f + __builtin_amdgcn_exp2f(az));
        const float r  = __builtin_amdgcn_rcpf(1.0f + __builtin_amdgcn_exp2f(ar));
        const float tt = fmaf(r, ah, ax);
        const float n  = fmaf(-2.0f,
                              __builtin_amdgcn_rcpf(1.0f + __builtin_amdgcn_exp2f(tt)),
                              1.0f);

        const float hj = (j == 0) ? hv.x : (j == 1) ? hv.y : (j == 2) ? hv.z : hv.w;
        o[k] = fmaf(z, hj - n, n);       // (1-z)*n + z*h
    }

    // ---- transpose through LDS (pad-5: <=2-way banks) -> dense stores ----
    __syncthreads();                     // all waves done reading xs
#pragma unroll
    for (int k = 0; k < 8; ++k)
        xs[(lane + (k << 6)) * 5 + j] = o[k];
    __syncthreads();

    float* op = out + tile * DHc;
#pragma unroll
    for (int k = 0; k < 8; ++k) {
        const int m = (k << 8) + t;      // element index within tile
        op[m] = xs[(m >> 2) * 5 + (t & 3)];
    }
}

extern "C" void kernel_launch(void* const* d_in, const int* in_sizes, int n_in,
                              void* d_out, int out_size, void* d_ws, size_t ws_size,
                              hipStream_t stream) {
    const float* x   = (const float*)d_in[0];
    const float* h   = (const float*)d_in[1];
    const float* Wzh = (const float*)d_in[2];
    const float* bzh = (const float*)d_in[3];
    const float* Wzx = (const float*)d_in[4];
    const float* bzx = (const float*)d_in[5];
    const float* Wrh = (const float*)d_in[6];
    const float* brh = (const float*)d_in[7];
    const float* Wrx = (const float*)d_in[8];
    const float* brx = (const float*)d_in[9];
    const float* Wnx = (const float*)d_in[10];
    const float* bnx = (const float*)d_in[11];
    const float* Wnh = (const float*)d_in[12];
    const float* bnh = (const float*)d_in[13];
    float* out = (float*)d_out;

    const int nrows = out_size / DHc;    // 4,194,304
    const int grid  = nrows / TR;        // 8192 blocks, exact
    gru_fused<<<grid, 256, 0, stream>>>(x, h, Wzh, bzh, Wzx, bzx,
                                        Wrh, brh, Wrx, brx,
                                        Wnx, bnx, Wnh, bnh, out);
}